// Round 9
// baseline (8691.552 us; speedup 1.0000x reference)
//
#include <hip/hip_runtime.h>
#include <math.h>

#define B_SZ   32
#define T_SZ   1024
#define IN_SZ  512
#define SEN    512
#define HID    1024
#define MOT    512
#define OUT_SZ 512

#define K2     512         // f16-pair dwords per h row
#define NWAVE  128         // independent scan waves (blocks of 64)

typedef __fp16  f16x8 __attribute__((ext_vector_type(8)));
typedef float   f32x4 __attribute__((ext_vector_type(4)));

__device__ inline uint32_t pk16(float a, float b) {
  auto p = __builtin_amdgcn_cvt_pkrtz(a, b);
  return __builtin_bit_cast(uint32_t, p);
}

// ---------------------------------------------------------------------------
// Generic tiled f32 GEMM:  C[scatter(r), c] = sum_k A[r,k] * op(B)[k,c] + bias[c]
//   TB=true : Bm is [N][K] row-major (A @ B^T);  TB=false: Bm is [K][N] (A @ B)
//   C address for row r, col c:  (r % P)*S1 + (r / P)*S2 + c
// ---------------------------------------------------------------------------
template<bool TB>
__global__ __launch_bounds__(256) void gemm_tiled(
    const float* __restrict__ A, const float* __restrict__ Bm,
    const float* __restrict__ bias, float* __restrict__ C,
    int M, int N, int K, int lda,
    int P, long long S1, long long S2)
{
  __shared__ float As[16][64 + 1];
  __shared__ float Bs[16][64 + 1];
  const int tid = threadIdx.x;
  const int n0 = blockIdx.x * 64;
  const int r0 = blockIdx.y * 64;
  const int ty = tid / 16;
  const int tx = tid % 16;

  float acc[4][4] = {};

  for (int k0 = 0; k0 < K; k0 += 16) {
    {
      const int kk = tid % 16, m0 = tid / 16;
      #pragma unroll
      for (int i = 0; i < 4; i++) {
        const int m = m0 + i * 16;
        As[kk][m] = A[(long long)(r0 + m) * lda + k0 + kk];
      }
    }
    if (TB) {
      const int kk = tid % 16, nl0 = tid / 16;
      #pragma unroll
      for (int i = 0; i < 4; i++) {
        const int n = nl0 + i * 16;
        Bs[kk][n] = Bm[(long long)(n0 + n) * K + k0 + kk];
      }
    } else {
      const int nl = tid % 64, kk0 = tid / 64;
      #pragma unroll
      for (int i = 0; i < 4; i++) {
        const int kk = kk0 + i * 4;
        Bs[kk][nl] = Bm[(long long)(k0 + kk) * N + n0 + nl];
      }
    }
    __syncthreads();

    #pragma unroll
    for (int kk = 0; kk < 16; kk++) {
      float av[4], bv[4];
      #pragma unroll
      for (int i = 0; i < 4; i++) av[i] = As[kk][ty * 4 + i];
      #pragma unroll
      for (int j = 0; j < 4; j++) bv[j] = Bs[kk][tx * 4 + j];
      #pragma unroll
      for (int i = 0; i < 4; i++)
        #pragma unroll
        for (int j = 0; j < 4; j++)
          acc[i][j] += av[i] * bv[j];
    }
    __syncthreads();
  }

  #pragma unroll
  for (int i = 0; i < 4; i++) {
    const int r = r0 + ty * 4 + i;
    const long long base = (long long)(r % P) * S1 + (long long)(r / P) * S2;
    #pragma unroll
    for (int j = 0; j < 4; j++) {
      const int c = n0 + tx * 4 + j;
      float v = acc[i][j];
      if (bias) v += bias[c];
      C[base + c] = v;
    }
  }
}

// bias_eff[h] = b_cell[h] + dot(W_x[h,:], b_in)
__global__ void bias_eff_kernel(const float* __restrict__ Wx,
                                const float* __restrict__ b_in,
                                const float* __restrict__ b_cell,
                                float* __restrict__ bias_eff)
{
  const int h = blockIdx.x * 256 + threadIdx.x;
  float s = b_cell[h];
  for (int k = 0; k < SEN; k++) s += Wx[h * SEN + k] * b_in[k];
  bias_eff[h] = s;
}

// Pack W_h f32 [j][k] -> Wp16 u32 [j][k2]
__global__ __launch_bounds__(256) void pack_wh16_kernel(
    const float* __restrict__ Wh, uint32_t* __restrict__ Wp16)
{
  const int idx = blockIdx.x * 256 + threadIdx.x;
  const float2 v = *(const float2*)(Wh + (size_t)idx * 2);
  Wp16[idx] = pk16(v.x, v.y);
}

// Pack init_h f32 [B][HID] -> hx[0] ([B][K2] u32 f16-pairs)
__global__ __launch_bounds__(256) void init_hx_kernel(
    const float* __restrict__ init_h, uint32_t* __restrict__ hx0)
{
  const int idx = blockIdx.x * 256 + threadIdx.x;      // b*K2 + k2
  const float2 v = *(const float2*)(init_h + (size_t)idx * 2);
  hx0[idx] = pk16(v.x, v.y);
}

// ---------------------------------------------------------------------------
// Scan v7: 128 INDEPENDENT waves (128 blocks x 64 threads), zero LDS, zero
// __syncthreads. Wave wid = (jblk = wid>>1, qr = wid&1) computes the
// 16b x 16j tile (b-half qr, j-slice jblk) of h @ W_h^T each step via
// mfma_f32_16x16x32_f16:
//   - W fragments live in 128 VGPRs (loaded once; wave has full VGPR budget)
//   - A fragments load DIRECTLY from the hx exchange buffer as device-scope
//     relaxed 8B atomic loads (hx layout == MFMA A-operand layout)
//   - per-step sync: poll 128 per-wave flags (2/lane + __all), publish own
//     16 dwords, s_waitcnt vmcnt(0), store own flag. No barriers.
// hx double-buffered by step parity; hx[0] pre-filled from init_h.
// ---------------------------------------------------------------------------
__global__ __launch_bounds__(64, 1) void scan_w_kernel(
    const float* __restrict__ init_h,
    const uint32_t* __restrict__ Wp16,   // [HID][K2]
    const float* __restrict__ pre,       // [T][B][HID]
    const float* __restrict__ tsp,       // [B][T]
    const float* __restrict__ Avec,
    const float* __restrict__ tau,
    float* __restrict__ hseq,            // [T][B][MOT]
    uint32_t* __restrict__ hx,           // [2][B][K2]
    uint32_t* __restrict__ flags,        // [NWAVE][16]
    float* __restrict__ last_state)      // [B][HID]
{
  const int wid   = blockIdx.x;          // 0..127
  const int lane  = threadIdx.x;         // 0..63
  const int qr    = wid & 1;             // b-half
  const int jblk  = wid >> 1;            // 0..63
  const int row16 = lane & 15;
  const int kg    = lane >> 4;           // 0..3

  const int j_glob = jblk * 16 + row16;
  const int b0     = qr * 16 + kg * 4;   // first of 4 owned b's

  // W fragments -> registers (once)
  uint4 wreg[32];
  {
    const uint32_t* wrow = Wp16 + (size_t)j_glob * K2;
    #pragma unroll
    for (int kk = 0; kk < 32; ++kk)
      wreg[kk] = *(const uint4*)(wrow + kk * 16 + kg * 4);
  }

  const float a_j  = Avec[j_glob];
  const float it_j = 1.f / tau[j_glob];
  float h_old[4];
  #pragma unroll
  for (int r = 0; r < 4; ++r) h_old[r] = init_h[(b0 + r) * HID + j_glob];

  float prevC[4], tsC[4];
  #pragma unroll
  for (int r = 0; r < 4; ++r) {
    prevC[r] = pre[(size_t)(b0 + r) * HID + j_glob];
    tsC[r]   = tsp[(b0 + r) * T_SZ + 0];
  }

  const size_t abase = (size_t)(qr * 16 + row16) * (K2 / 2) + kg * 2;  // u64 units

  for (int t = 0; t < T_SZ; ++t) {
    // wait until every wave has published h(t) (posted as flag value t)
    if (t > 0) {
      const uint32_t tgt = (uint32_t)t;
      while (true) {
        const uint32_t v0 = __hip_atomic_load(&flags[lane * 16],
                              __ATOMIC_RELAXED, __HIP_MEMORY_SCOPE_AGENT);
        const uint32_t v1 = __hip_atomic_load(&flags[(lane + 64) * 16],
                              __ATOMIC_RELAXED, __HIP_MEMORY_SCOPE_AGENT);
        if (__all((v0 >= tgt) && (v1 >= tgt))) break;
        __builtin_amdgcn_s_sleep(1);
      }
    }

    // A fragments straight from the exchange buffer (coherent 8B loads)
    const unsigned long long* hxr =
        (const unsigned long long*)(hx + (t & 1) * (B_SZ * K2));
    unsigned long long a0[32], a1[32];
    #pragma unroll
    for (int kk = 0; kk < 32; ++kk) {
      a0[kk] = __hip_atomic_load(&hxr[abase + kk * 8],
                                 __ATOMIC_RELAXED, __HIP_MEMORY_SCOPE_AGENT);
      a1[kk] = __hip_atomic_load(&hxr[abase + kk * 8 + 1],
                                 __ATOMIC_RELAXED, __HIP_MEMORY_SCOPE_AGENT);
    }

    f32x4 acc = {0.f, 0.f, 0.f, 0.f};
    #pragma unroll
    for (int kk = 0; kk < 32; ++kk) {
      const uint4 av = make_uint4((uint32_t)a0[kk], (uint32_t)(a0[kk] >> 32),
                                  (uint32_t)a1[kk], (uint32_t)(a1[kk] >> 32));
      acc = __builtin_amdgcn_mfma_f32_16x16x32_f16(
          __builtin_bit_cast(f16x8, av), __builtin_bit_cast(f16x8, wreg[kk]),
          acc, 0, 0, 0);
    }

    // liquid update for 4 owned (b, j) cells
    float hn[4];
    #pragma unroll
    for (int r = 0; r < 4; ++r) {
      const float z = acc[r] + prevC[r];
      const float f = 1.f / (1.f + __expf(-z));
      hn[r] = (h_old[r] + tsC[r] * f * a_j) / (1.f + tsC[r] * (it_j + f));
      h_old[r] = hn[r];
    }

    // publish (even-j lanes store f16 pairs)
    uint32_t* hxw = hx + ((t + 1) & 1) * (B_SZ * K2);
    #pragma unroll
    for (int r = 0; r < 4; ++r) {
      const float partner = __shfl_xor(hn[r], 1);
      if ((row16 & 1) == 0)
        __hip_atomic_store(&hxw[(b0 + r) * K2 + jblk * 8 + (row16 >> 1)],
                           pk16(hn[r], partner),
                           __ATOMIC_RELAXED, __HIP_MEMORY_SCOPE_AGENT);
    }
    if (jblk < 32) {   // motor half -> hseq f32
      #pragma unroll
      for (int r = 0; r < 4; ++r)
        hseq[(size_t)t * (B_SZ * MOT) + (b0 + r) * MOT + j_glob] = hn[r];
    }

    // prefetch next step's pre/ts (overlaps with store drain)
    const int tn = (t + 1 < T_SZ) ? t + 1 : t;
    #pragma unroll
    for (int r = 0; r < 4; ++r) {
      prevC[r] = pre[(size_t)tn * (B_SZ * HID) + (b0 + r) * HID + j_glob];
      tsC[r]   = tsp[(b0 + r) * T_SZ + tn];
    }

    asm volatile("s_waitcnt vmcnt(0)" ::: "memory");   // hx stores visible
    if (lane == 0)
      __hip_atomic_store(&flags[wid * 16], (uint32_t)(t + 1),
                         __ATOMIC_RELAXED, __HIP_MEMORY_SCOPE_AGENT);
  }

  #pragma unroll
  for (int r = 0; r < 4; ++r)
    last_state[(b0 + r) * HID + j_glob] = h_old[r];
}

extern "C" void kernel_launch(void* const* d_in, const int* in_sizes, int n_in,
                              void* d_out, int out_size, void* d_ws, size_t ws_size,
                              hipStream_t stream)
{
  const float* inputs    = (const float*)d_in[0];
  const float* timespans = (const float*)d_in[1];
  const float* init_h    = (const float*)d_in[2];
  const float* W_in      = (const float*)d_in[3];
  const float* b_in      = (const float*)d_in[4];
  const float* W_x       = (const float*)d_in[5];
  const float* W_h       = (const float*)d_in[6];
  const float* b_cell    = (const float*)d_in[7];
  const float* tau       = (const float*)d_in[8];
  const float* A         = (const float*)d_in[9];
  const float* W_out     = (const float*)d_in[10];
  const float* b_out     = (const float*)d_in[11];
  float* out = (float*)d_out;

  float*    ws    = (float*)d_ws;
  float*    pre   = ws;                                  // T*B*HID f32
  float*    hseq  = pre   + (size_t)T_SZ * B_SZ * HID;   // T*B*MOT f32
  float*    WxiWp = hseq  + (size_t)T_SZ * B_SZ * MOT;   // HID*IN_SZ (Wxi f32 -> Wp16 u32)
  float*    beff  = WxiWp + (size_t)HID * IN_SZ;         // HID
  uint32_t* hx    = (uint32_t*)(beff + HID);             // 2*B*K2
  uint32_t* flags = hx + 2 * B_SZ * K2;                  // NWAVE*16 u32

  // K0: Wxi = W_x @ W_in  (fold input projection into cell GEMM)
  gemm_tiled<false><<<dim3(IN_SZ / 64, HID / 64), 256, 0, stream>>>(
      W_x, W_in, nullptr, WxiWp, HID, IN_SZ, SEN, SEN,
      1 << 30, (long long)IN_SZ, 0LL);

  bias_eff_kernel<<<HID / 256, 256, 0, stream>>>(W_x, b_in, b_cell, beff);

  // K1: pre[t][b][h] = inputs[r=b*T+t,:] @ Wxi^T + beff
  gemm_tiled<true><<<dim3(HID / 64, (B_SZ * T_SZ) / 64), 256, 0, stream>>>(
      inputs, WxiWp, beff, pre, B_SZ * T_SZ, HID, IN_SZ, IN_SZ,
      T_SZ, (long long)B_SZ * HID, (long long)HID);

  // K2a: pack W_h -> f16x2 (overwrites Wxi slot; safe by stream order)
  pack_wh16_kernel<<<(HID * K2) / 256, 256, 0, stream>>>(W_h, (uint32_t*)WxiWp);

  // K2b: init exchange buffer parity-0 with packed init_h; zero flags
  init_hx_kernel<<<(B_SZ * K2) / 256, 256, 0, stream>>>(init_h, hx);
  (void)hipMemsetAsync(flags, 0, NWAVE * 16 * sizeof(uint32_t), stream);

  // K2c: the scan — 128 co-resident independent waves
  {
    const uint32_t* Wp16c = (const uint32_t*)WxiWp;
    float* last_state = out + (size_t)B_SZ * T_SZ * OUT_SZ;
    void* args[] = {
      (void*)&init_h, (void*)&Wp16c, (void*)&pre, (void*)&timespans,
      (void*)&A, (void*)&tau, (void*)&hseq, (void*)&hx, (void*)&flags,
      (void*)&last_state
    };
    (void)hipLaunchCooperativeKernel((void*)scan_w_kernel, dim3(NWAVE), dim3(64),
                                     args, 0, stream);
  }

  // K3: out[b][t][o] = hseq[r=t*B+b, :MOT] @ W_out^T + b_out
  gemm_tiled<true><<<dim3(OUT_SZ / 64, (B_SZ * T_SZ) / 64), 256, 0, stream>>>(
      hseq, W_out, b_out, out, B_SZ * T_SZ, OUT_SZ, MOT, MOT,
      B_SZ, (long long)T_SZ * OUT_SZ, (long long)OUT_SZ);
}